// Round 2
// baseline (17.250 us; speedup 1.0000x reference)
//
#include <hip/hip_runtime.h>
#include <math.h>

#define NW  12            // N_WIRES
#define BPB 8             // batches per block
#define NT  128           // 2 waves; 96 active threads in compute phases
#define ROW (NW * NW)     // 144 floats per batch

// Analytic form of the quantum circuit:
//   phi_v = x[b, v, e] + theta[v]
//   q[b, w, e] = prod_{v=0..w} cos(phi_v)        (w >= 1)
//   q[b, 0, e] = prod_{v=1..11} cos(phi_v)
//   out[b, w, j] = b_out[j] + sum_e q[b,w,e] * W_out[j,e]
__global__ __launch_bounds__(NT) void qsa_kernel(
    const float* __restrict__ x,      // (B, 12, 12)
    const float* __restrict__ theta,  // (12,)
    const float* __restrict__ Wout,   // (12, 12)
    const float* __restrict__ bout,   // (12,)
    float* __restrict__ out)          // (B, 12, 12)
{
    __shared__ float xs[BPB * ROW];       // staged x: [b][v][e]
    __shared__ float qs[BPB][NW][NW + 1]; // [b][w][e], padded to kill bank aliasing
    __shared__ float Ws[ROW];
    __shared__ float th[NW];
    __shared__ float bo[NW];

    const int t  = threadIdx.x;
    const int b0 = blockIdx.x * BPB;

    if (t < 128) Ws[t] = Wout[t];
    if (t < ROW - 128) Ws[128 + t] = Wout[128 + t];
    if (t < NW) { th[t] = theta[t]; bo[t] = bout[t]; }

    // Coalesced stage of 8 batches (1152 floats) into LDS: 9 per thread.
    const float* xg = x + (size_t)b0 * ROW;
    #pragma unroll
    for (int i = 0; i < BPB * ROW / NT; ++i)
        xs[t + i * NT] = xg[t + i * NT];

    __syncthreads();

    if (t < BPB * NW) {
        // Phase 1: one thread per (batch, head e): cosines + prefix products.
        const int b = t / NW;
        const int e = t % NW;
        float c[NW];
        #pragma unroll
        for (int v = 0; v < NW; ++v)
            c[v] = __cosf(xs[b * ROW + v * NW + e] + th[v]);

        float q[NW];
        float pref = c[0];
        #pragma unroll
        for (int w = 1; w < NW; ++w) { pref *= c[w]; q[w] = pref; }
        float p0 = c[1];
        #pragma unroll
        for (int v = 2; v < NW; ++v) p0 *= c[v];
        q[0] = p0;

        #pragma unroll
        for (int w = 0; w < NW; ++w) qs[b][w][e] = q[w];
    }

    __syncthreads();

    if (t < BPB * NW) {
        // Phase 2: one thread per (batch, wire w): 12-wide GEMV + bias, write row.
        const int b = t / NW;
        const int w = t % NW;
        float acc[NW];
        #pragma unroll
        for (int j = 0; j < NW; ++j) acc[j] = bo[j];
        #pragma unroll
        for (int e = 0; e < NW; ++e) {
            const float qv = qs[b][w][e];
            #pragma unroll
            for (int j = 0; j < NW; ++j)
                acc[j] = fmaf(qv, Ws[j * NW + e], acc[j]);
        }
        // Row base offset = ((b0+b)*12 + w)*12 floats = multiple of 48 B: 16B-aligned.
        float* og = out + ((size_t)(b0 + b) * NW + (size_t)w) * NW;
        float4* o4 = (float4*)og;
        o4[0] = make_float4(acc[0], acc[1],  acc[2],  acc[3]);
        o4[1] = make_float4(acc[4], acc[5],  acc[6],  acc[7]);
        o4[2] = make_float4(acc[8], acc[9],  acc[10], acc[11]);
    }
}

extern "C" void kernel_launch(void* const* d_in, const int* in_sizes, int n_in,
                              void* d_out, int out_size, void* d_ws, size_t ws_size,
                              hipStream_t stream) {
    const float* x     = (const float*)d_in[0];
    const float* theta = (const float*)d_in[1];
    const float* Wout  = (const float*)d_in[2];
    const float* bout  = (const float*)d_in[3];
    float* out = (float*)d_out;

    const int B = in_sizes[0] / ROW;   // 2048
    const int grid = B / BPB;          // 256 blocks -> one per CU
    qsa_kernel<<<grid, NT, 0, stream>>>(x, theta, Wout, bout, out);
}

// Round 3
// 9.420 us; speedup vs baseline: 1.8312x; 1.8312x over previous
//
#include <hip/hip_runtime.h>
#include <math.h>

#define NW  12            // N_WIRES
#define BPB 16            // batches per block
#define NT  (BPB * NW)    // 192 threads (3 waves), ALL active in every phase
#define ROW (NW * NW)     // 144 floats per batch

// Analytic form of the quantum circuit:
//   phi_v = x[b, v, e] + theta[v]
//   q[b, w, e] = prod_{v=0..w} cos(phi_v)        (w >= 1)
//   q[b, 0, e] = prod_{v=1..11} cos(phi_v)
//   out[b, w, j] = b_out[j] + sum_e q[b,w,e] * W_out[j,e]
__global__ __launch_bounds__(NT) void qsa_kernel(
    const float* __restrict__ x,      // (B, 12, 12)
    const float* __restrict__ theta,  // (12,)
    const float* __restrict__ Wout,   // (12, 12)
    const float* __restrict__ bout,   // (12,)
    float* __restrict__ out)          // (B, 12, 12)
{
    __shared__ float xs[BPB * ROW];       // staged x: [b][v][e]
    __shared__ float qs[BPB][NW][NW + 1]; // [b][w][e], padded: batch stride 156 breaks bank aliasing
    __shared__ float Ws[ROW];
    __shared__ float th[NW];
    __shared__ float bo[NW];

    const int t  = threadIdx.x;
    const int b0 = blockIdx.x * BPB;

    if (t < ROW) Ws[t] = Wout[t];
    if (t < NW) { th[t] = theta[t]; bo[t] = bout[t]; }

    // Coalesced stage of 16 batches (2304 floats) into LDS: 12 per thread.
    const float* xg = x + (size_t)b0 * ROW;
    #pragma unroll
    for (int i = 0; i < NW; ++i)
        xs[t + i * NT] = xg[t + i * NT];

    __syncthreads();

    // Phase 1: one thread per (batch, head e): cosines + prefix products.
    {
        const int b = t / NW;
        const int e = t % NW;
        float c[NW];
        #pragma unroll
        for (int v = 0; v < NW; ++v)
            c[v] = __cosf(xs[b * ROW + v * NW + e] + th[v]);

        float q[NW];
        float pref = c[0];
        #pragma unroll
        for (int w = 1; w < NW; ++w) { pref *= c[w]; q[w] = pref; }
        float p0 = c[1];
        #pragma unroll
        for (int v = 2; v < NW; ++v) p0 *= c[v];
        q[0] = p0;

        #pragma unroll
        for (int w = 0; w < NW; ++w) qs[b][w][e] = q[w];
    }

    __syncthreads();

    // Phase 2: one thread per (batch, wire w): 12-wide GEMV + bias, write row.
    {
        const int b = t / NW;
        const int w = t % NW;
        float acc[NW];
        #pragma unroll
        for (int j = 0; j < NW; ++j) acc[j] = bo[j];
        #pragma unroll
        for (int e = 0; e < NW; ++e) {
            const float qv = qs[b][w][e];
            #pragma unroll
            for (int j = 0; j < NW; ++j)
                acc[j] = fmaf(qv, Ws[j * NW + e], acc[j]);
        }
        // Row base offset = ((b0+b)*12 + w)*12 floats = multiple of 48 B: 16B-aligned.
        float* og = out + ((size_t)(b0 + b) * NW + (size_t)w) * NW;
        float4* o4 = (float4*)og;
        o4[0] = make_float4(acc[0], acc[1],  acc[2],  acc[3]);
        o4[1] = make_float4(acc[4], acc[5],  acc[6],  acc[7]);
        o4[2] = make_float4(acc[8], acc[9],  acc[10], acc[11]);
    }
}

extern "C" void kernel_launch(void* const* d_in, const int* in_sizes, int n_in,
                              void* d_out, int out_size, void* d_ws, size_t ws_size,
                              hipStream_t stream) {
    const float* x     = (const float*)d_in[0];
    const float* theta = (const float*)d_in[1];
    const float* Wout  = (const float*)d_in[2];
    const float* bout  = (const float*)d_in[3];
    float* out = (float*)d_out;

    const int B = in_sizes[0] / ROW;   // 2048
    const int grid = B / BPB;          // 128
    qsa_kernel<<<grid, NT, 0, stream>>>(x, theta, Wout, bout, out);
}